// Round 5
// baseline (280.031 us; speedup 1.0000x reference)
//
#include <hip/hip_runtime.h>

#define DIM 128

typedef float fx4 __attribute__((ext_vector_type(4)));

// first index i in [0,n) with seg[i] >= val  (seg sorted ascending)
__device__ __forceinline__ int lb_search(const int* __restrict__ seg, int n, int val) {
    int lo = 0, hi = n;
    while (lo < hi) {
        int mid = (lo + hi) >> 1;
        if (seg[mid] < val) lo = mid + 1; else hi = mid;
    }
    return lo;
}

// ---------------------------------------------------------------------------
// Kernel 1: segment sums. 8 blocks per graph (q = eighth), 256 threads:
// tx (0..31) = float4 column, ty (0..7) = row slot. Dual accumulators for
// MLP. Deterministic per-eighth partials (no atomics). partial: [8][G][DIM].
// Graph bounds come from a uniform binary search of the sorted seg array
// (~2x20 probes, L1-broadcast) — no separate offsets kernel/pass.
// L3 discipline: blocks entirely below cut_row use nontemporal loads so the
// head of h never allocates in Infinity Cache; only the ~218 MB tail stays
// resident for k_scatter's tail-first walk.
// ---------------------------------------------------------------------------
__global__ __launch_bounds__(256) void k_segsum(const float* __restrict__ h,
                                                const int* __restrict__ seg,
                                                float* __restrict__ partial,
                                                int nrows, int ngraphs, int cut_row) {
    const int b = blockIdx.x;
    const int g = b >> 3;
    const int q = b & 7;
    const int s = lb_search(seg, nrows, g);
    const int e = lb_search(seg, nrows, g + 1);
    const int n = e - s;
    const int per = (n + 7) >> 3;
    const int rs = s + q * per;
    const int re = min(rs + per, e);

    const int tx = threadIdx.x & 31;   // float4 column
    const int ty = threadIdx.x >> 5;   // row slot (8 rows in flight)

    fx4 acc  = {0.f, 0.f, 0.f, 0.f};
    fx4 acc2 = {0.f, 0.f, 0.f, 0.f};
    int r = rs + ty;
    if (re <= cut_row) {               // head region: bypass cache allocation
        for (; r + 8 < re; r += 16) {
            acc  += __builtin_nontemporal_load(
                        reinterpret_cast<const fx4*>(h + (size_t)r * DIM + tx * 4));
            acc2 += __builtin_nontemporal_load(
                        reinterpret_cast<const fx4*>(h + (size_t)(r + 8) * DIM + tx * 4));
        }
        if (r < re)
            acc += __builtin_nontemporal_load(
                       reinterpret_cast<const fx4*>(h + (size_t)r * DIM + tx * 4));
    } else {                           // tail region: allocate (stays in L3)
        for (; r + 8 < re; r += 16) {
            acc  += *reinterpret_cast<const fx4*>(h + (size_t)r * DIM + tx * 4);
            acc2 += *reinterpret_cast<const fx4*>(h + (size_t)(r + 8) * DIM + tx * 4);
        }
        if (r < re)
            acc += *reinterpret_cast<const fx4*>(h + (size_t)r * DIM + tx * 4);
    }
    acc += acc2;

    __shared__ fx4 red[8][32];
    red[ty][tx] = acc;
    __syncthreads();
    if (ty == 0) {
        fx4 t = red[0][tx];
        #pragma unroll
        for (int i = 1; i < 8; ++i) t += red[i][tx];
        *reinterpret_cast<fx4*>(
            partial + ((size_t)q * ngraphs + g) * DIM + tx * 4) = t;
    }
}

// ---------------------------------------------------------------------------
// Kernel 2: virtual-node update. One block per graph, 128 threads.
// pool = sum/count ; x = vn_h + pool ; vn_new = vn_h + relu(x @ W + b)
// Count via binary search (uniform, cached).
// ---------------------------------------------------------------------------
__global__ __launch_bounds__(128) void k_vn(const float* __restrict__ vn_h,
                                            const float* __restrict__ W,
                                            const float* __restrict__ bias,
                                            const float* __restrict__ partial,
                                            const int* __restrict__ seg,
                                            float* __restrict__ vn_out,
                                            int nrows, int ngraphs) {
    const int g = blockIdx.x;
    const int d = threadIdx.x;
    const int cnt = lb_search(seg, nrows, g + 1) - lb_search(seg, nrows, g);
    const float inv = 1.0f / (float)max(cnt, 1);

    float sum = 0.f;
    #pragma unroll
    for (int p = 0; p < 8; ++p)
        sum += partial[((size_t)p * ngraphs + g) * DIM + d];
    const float vh = vn_h[(size_t)g * DIM + d];
    const float x = vh + sum * inv;

    __shared__ float xs[DIM];
    xs[d] = x;
    __syncthreads();

    float dot = bias[d];
    #pragma unroll
    for (int k = 0; k < DIM; ++k)
        dot = fmaf(xs[k], W[k * DIM + d], dot);

    vn_out[(size_t)g * DIM + d] = vh + fmaxf(dot, 0.0f);
}

// ---------------------------------------------------------------------------
// Kernel 3: h_new = h + vn_new[seg]. Grid-stride float4 stream, TAIL-FIRST
// two-segment ascending mapping: the first tail_len work items cover
// [cut4, total4) ascending (the L3-resident tail k_segsum left behind, hot
// in the earliest iterations), the rest cover [0, cut4) ascending. Regular
// (allocating) loads for h so L3 hits are served; nontemporal stores for
// h_out (pure streaming, never re-read, must not evict the h tail).
// ---------------------------------------------------------------------------
__global__ __launch_bounds__(256) void k_scatter(const float* __restrict__ h,
                                                 const int* __restrict__ seg,
                                                 const float* __restrict__ vn_new,
                                                 float* __restrict__ h_out,
                                                 int n, int cut_row) {
    const int total4 = n * (DIM / 4);          // float4 elements (32e6 < 2^31)
    const int cut4 = cut_row * (DIM / 4);
    const int tail_len = total4 - cut4;
    const int stride = gridDim.x * blockDim.x;
    for (int i = blockIdx.x * blockDim.x + threadIdx.x; i < total4; i += stride) {
        const int j = (i < tail_len) ? (cut4 + i) : (i - tail_len);
        const int r = j >> 5;                  // row
        const int c = (j & 31) * 4;            // float col
        const int g = seg[r];
        const fx4 hv = *reinterpret_cast<const fx4*>(h + (size_t)r * DIM + c);
        const fx4 vv = *reinterpret_cast<const fx4*>(vn_new + (size_t)g * DIM + c);
        const fx4 o = hv + vv;
        __builtin_nontemporal_store(
            o, reinterpret_cast<fx4*>(h_out + (size_t)r * DIM + c));
    }
}

// ---------------------------------------------------------------------------
extern "C" void kernel_launch(void* const* d_in, const int* in_sizes, int n_in,
                              void* d_out, int out_size, void* d_ws, size_t ws_size,
                              hipStream_t stream) {
    const float* h    = (const float*)d_in[0];
    const float* vn_h = (const float*)d_in[1];
    const int*   seg  = (const int*)d_in[2];
    const float* W    = (const float*)d_in[3];
    const float* bias = (const float*)d_in[4];

    const int N = in_sizes[0] / DIM;   // 1,000,000
    const int G = in_sizes[1] / DIM;   // 1024

    float* out    = (float*)d_out;
    float* vn_out = out;                       // [G*DIM]
    float* h_out  = out + (size_t)G * DIM;     // [N*DIM]

    // Scratch: partial sums [8][G][DIM] f32.
    const size_t partial_floats = (size_t)8 * G * DIM;
    const size_t need = partial_floats * sizeof(float);

    float* partial;
    if (ws_size >= need) {
        partial = (float*)d_ws;
    } else {
        // Stash scratch inside the h_new region of d_out; it is fully
        // consumed by k_vn before k_scatter overwrites it.
        partial = h_out;
    }

    // Rows >= cut_row (~218 MB tail) are allowed to allocate in L3;
    // everything below streams via nt-loads.
    int cut_row = N - 425000;
    if (cut_row < 0) cut_row = 0;

    hipLaunchKernelGGL(k_segsum, dim3(G * 8), dim3(256), 0, stream,
                       h, seg, partial, N, G, cut_row);
    hipLaunchKernelGGL(k_vn, dim3(G), dim3(DIM), 0, stream,
                       vn_h, W, bias, partial, seg, vn_out, N, G);

    const int total4 = N * (DIM / 4);
    int nb = (total4 + 255) / 256;
    if (nb > 2048) nb = 2048;
    hipLaunchKernelGGL(k_scatter, dim3(nb), dim3(256), 0, stream,
                       h, seg, vn_out, h_out, N, cut_row);
}

// Round 6
// 263.622 us; speedup vs baseline: 1.0622x; 1.0622x over previous
//
#include <hip/hip_runtime.h>

#define DIM 128

typedef float fx4 __attribute__((ext_vector_type(4)));

// ---------------------------------------------------------------------------
// Kernel 1: per-graph start offsets from sorted segment_ids.
// offs[g] = first row with seg >= g ; offs[G] = N. Handles empty graphs.
// (Restored from R4 — replacing it with per-block binary search serialized
// segsum startup behind a ~40-deep dependent load chain and cost ~15 µs.)
// ---------------------------------------------------------------------------
__global__ void k_offsets(const int* __restrict__ seg, int* __restrict__ offs,
                          int n, int ngraphs) {
    const int i = blockIdx.x * blockDim.x + threadIdx.x;
    const int a = (i < n) ? seg[i] : 0;
    int p = __shfl_up(a, 1);          // all lanes participate before any exit
    if (i >= n) return;
    if (i == 0) {
        for (int g = 0; g <= a; ++g) offs[g] = 0;
    } else {
        if ((threadIdx.x & 63) == 0) p = seg[i - 1];   // wave boundary
        for (int g = p + 1; g <= a; ++g) offs[g] = i;
    }
    if (i == n - 1) {
        for (int g = a + 1; g <= ngraphs; ++g) offs[g] = n;
    }
}

// ---------------------------------------------------------------------------
// Kernel 2: segment sums. 8 blocks per graph (q = eighth), 256 threads:
// tx (0..31) = float4 column, ty (0..7) = row slot. Dual accumulators.
// Deterministic per-eighth partials (no atomics). partial: [8][G][DIM].
// ALL loads allocate in L3 (ping-pong scheme): the ascending sweep (a) HITS
// the head-of-h residency left by the previous replay's descending scatter,
// and (b) leaves the tail of h resident for this replay's scatter.
// ---------------------------------------------------------------------------
__global__ __launch_bounds__(256) void k_segsum(const float* __restrict__ h,
                                                const int* __restrict__ offs,
                                                float* __restrict__ partial,
                                                int ngraphs) {
    const int b = blockIdx.x;
    const int g = b >> 3;
    const int q = b & 7;
    const int s = offs[g];
    const int e = offs[g + 1];
    const int n = e - s;
    const int per = (n + 7) >> 3;
    const int rs = s + q * per;
    const int re = min(rs + per, e);

    const int tx = threadIdx.x & 31;   // float4 column
    const int ty = threadIdx.x >> 5;   // row slot (8 rows in flight)

    fx4 acc  = {0.f, 0.f, 0.f, 0.f};
    fx4 acc2 = {0.f, 0.f, 0.f, 0.f};
    int r = rs + ty;
    for (; r + 8 < re; r += 16) {
        acc  += *reinterpret_cast<const fx4*>(h + (size_t)r * DIM + tx * 4);
        acc2 += *reinterpret_cast<const fx4*>(h + (size_t)(r + 8) * DIM + tx * 4);
    }
    if (r < re)
        acc += *reinterpret_cast<const fx4*>(h + (size_t)r * DIM + tx * 4);
    acc += acc2;

    __shared__ fx4 red[8][32];
    red[ty][tx] = acc;
    __syncthreads();
    if (ty == 0) {
        fx4 t = red[0][tx];
        #pragma unroll
        for (int i = 1; i < 8; ++i) t += red[i][tx];
        *reinterpret_cast<fx4*>(
            partial + ((size_t)q * ngraphs + g) * DIM + tx * 4) = t;
    }
}

// ---------------------------------------------------------------------------
// Kernel 3: virtual-node update. One block per graph, 128 threads.
// pool = sum/count ; x = vn_h + pool ; vn_new = vn_h + relu(x @ W + b)
// ---------------------------------------------------------------------------
__global__ __launch_bounds__(128) void k_vn(const float* __restrict__ vn_h,
                                            const float* __restrict__ W,
                                            const float* __restrict__ bias,
                                            const float* __restrict__ partial,
                                            const int* __restrict__ offs,
                                            float* __restrict__ vn_out,
                                            int ngraphs) {
    const int g = blockIdx.x;
    const int d = threadIdx.x;
    const int cnt = offs[g + 1] - offs[g];
    const float inv = 1.0f / (float)max(cnt, 1);

    float sum = 0.f;
    #pragma unroll
    for (int p = 0; p < 8; ++p)
        sum += partial[((size_t)p * ngraphs + g) * DIM + d];
    const float vh = vn_h[(size_t)g * DIM + d];
    const float x = vh + sum * inv;

    __shared__ float xs[DIM];
    xs[d] = x;
    __syncthreads();

    float dot = bias[d];
    #pragma unroll
    for (int k = 0; k < DIM; ++k)
        dot = fmaf(xs[k], W[k * DIM + d], dot);

    vn_out[(size_t)g * DIM + d] = vh + fmaxf(dot, 0.0f);
}

// ---------------------------------------------------------------------------
// Kernel 4: h_new = h + vn_new[seg]. Grid-stride float4 stream, DESCENDING
// walk (j = total-1-i): first consumes the L3-resident tail of h left by
// k_segsum's ascending sweep (allocating loads so hits are served and lines
// refreshed), then the cold head — leaving the HEAD of h resident for the
// NEXT replay's k_segsum (cross-replay ping-pong). h_out uses nontemporal
// stores only: the 512 MB write stream must never allocate in L3.
// ---------------------------------------------------------------------------
__global__ __launch_bounds__(256) void k_scatter(const float* __restrict__ h,
                                                 const int* __restrict__ seg,
                                                 const float* __restrict__ vn_new,
                                                 float* __restrict__ h_out,
                                                 int n) {
    const int total = n * (DIM / 4);           // float4 elements (32e6 < 2^31)
    const int stride = gridDim.x * blockDim.x;
    for (int i = blockIdx.x * blockDim.x + threadIdx.x; i < total; i += stride) {
        const int j = total - 1 - i;           // descending, still coalesced
        const int r = j >> 5;                  // row
        const int c = (j & 31) * 4;            // float col
        const int g = seg[r];
        const fx4 hv = *reinterpret_cast<const fx4*>(h + (size_t)r * DIM + c);
        const fx4 vv = *reinterpret_cast<const fx4*>(vn_new + (size_t)g * DIM + c);
        const fx4 o = hv + vv;
        __builtin_nontemporal_store(
            o, reinterpret_cast<fx4*>(h_out + (size_t)r * DIM + c));
    }
}

// ---------------------------------------------------------------------------
extern "C" void kernel_launch(void* const* d_in, const int* in_sizes, int n_in,
                              void* d_out, int out_size, void* d_ws, size_t ws_size,
                              hipStream_t stream) {
    const float* h    = (const float*)d_in[0];
    const float* vn_h = (const float*)d_in[1];
    const int*   seg  = (const int*)d_in[2];
    const float* W    = (const float*)d_in[3];
    const float* bias = (const float*)d_in[4];

    const int N = in_sizes[0] / DIM;   // 1,000,000
    const int G = in_sizes[1] / DIM;   // 1024

    float* out    = (float*)d_out;
    float* vn_out = out;                       // [G*DIM]
    float* h_out  = out + (size_t)G * DIM;     // [N*DIM]

    // Scratch: partial sums [8][G][DIM] f32 + offs [G+1] int.
    const size_t partial_floats = (size_t)8 * G * DIM;
    const size_t need = partial_floats * sizeof(float) + (size_t)(G + 1) * sizeof(int);

    float* partial;
    int*   offs;
    if (ws_size >= need) {
        partial = (float*)d_ws;
        offs    = (int*)((char*)d_ws + partial_floats * sizeof(float));
    } else {
        // Stash scratch inside the h_new region of d_out; it is fully
        // consumed by k_vn before k_scatter overwrites it.
        partial = h_out;
        offs    = (int*)(h_out + partial_floats);
    }

    hipLaunchKernelGGL(k_offsets, dim3((N + 255) / 256), dim3(256), 0, stream,
                       seg, offs, N, G);
    hipLaunchKernelGGL(k_segsum, dim3(G * 8), dim3(256), 0, stream,
                       h, offs, partial, G);
    hipLaunchKernelGGL(k_vn, dim3(G), dim3(DIM), 0, stream,
                       vn_h, W, bias, partial, offs, vn_out, G);

    const int total4 = N * (DIM / 4);
    int nb = (total4 + 255) / 256;
    if (nb > 2048) nb = 2048;
    hipLaunchKernelGGL(k_scatter, dim3(nb), dim3(256), 0, stream,
                       h, seg, vn_out, h_out, N);
}